// Round 2
// baseline (17495.174 us; speedup 1.0000x reference)
//
#include <hip/hip_runtime.h>

// ---------------------------------------------------------------------------
// self_LSTM_sparse_attn — MI355X persistent-kernel, full-fp32 (round 2).
//
// scores[t,b] = s_h[b] + s_mem[t,b]; s_h cancels in w = max(s - (kth+EPS), 0)
// => attention weights depend only on cached s_mem; w is <=4-sparse.
// WG g owns h dims {2g,2g+1}; its 8 gate rows live in LDS all 256 steps.
// mem[t][h][b] doubles as the h-broadcast (mem[i] == h_out(i-1)).
// Per-step cross-WG: mem write (128 B/WG), score partial (256 B/WG), one
// device-scope barrier. Score partials are double-buffered (no atomics).
// ---------------------------------------------------------------------------

#define T_N 256
#define B_N 64
#define I_N 256
#define H_N 512
#define C_N 64
#define EPSF 1e-7f
#define SLICE 32768u  // H_N*B_N floats per mem slice

// ws layout (float offsets)
#define XT_F    0u          // [T][I][B]   x transposed fp32     (4,194,304)
#define MEM_F   4194304u    // [T+1][H][B] h_out history         (8,421,376)
#define MSEQ_F  12615680u   // [T][H][B]   m_seq                 (8,388,608)
#define PSUM_F  21004288u   // [2][256][64] score partials       (32,768)
#define FCWT_F  21037056u   // [2H][C]     fc_w transposed       (65,536)
#define BAR_F   21102592u   // barrier counter                   (16)
#define TOT_F   21102608u

__device__ __forceinline__ float sigf(float x) { return 1.0f / (1.0f + expf(-x)); }

// insert s into descending top-5 (values v0..v4, indices j0..j3)
__device__ __forceinline__ void ins5(float s, int t,
                                     float& v0, float& v1, float& v2, float& v3, float& v4,
                                     int& j0, int& j1, int& j2, int& j3) {
  if (s > v4) {
    if (s > v0)      { v4=v3; v3=v2; j3=j2; v2=v1; j2=j1; v1=v0; j1=j0; v0=s; j0=t; }
    else if (s > v1) { v4=v3; v3=v2; j3=j2; v2=v1; j2=j1; v1=s; j1=t; }
    else if (s > v2) { v4=v3; v3=v2; j3=j2; v2=s; j2=t; }
    else if (s > v3) { v4=v3; v3=s; j3=t; }
    else             { v4=s; }
  }
}

__global__ void poison_k(float* out, int n) {
  int i = blockIdx.x * 256 + threadIdx.x;
  if (i < n) out[i] = __int_as_float(0x7fc00000);
}

// blocks 0..1023: transpose x -> xT[t][k][b]; blocks 1024..1039: fc_w -> fcwT[d][c]
__global__ void init_k(const float* __restrict__ x, const float* __restrict__ fc_w,
                       float* __restrict__ ws) {
  __shared__ float tile[64][65];
  const int blk = blockIdx.x, tid = threadIdx.x;
  if (blk < 1024) {
    const int t = blk >> 2, k0 = (blk & 3) * 64;
    for (int u = tid; u < 4096; u += 256) {
      int bb = u >> 6, kk = u & 63;
      tile[kk][bb] = x[((unsigned)t * 64u + bb) * 256u + k0 + kk];
    }
    __syncthreads();
    for (int u = tid; u < 4096; u += 256) {
      int kk = u >> 6, bb = u & 63;
      ws[XT_F + (unsigned)t * 16384u + (unsigned)(k0 + kk) * 64u + bb] = tile[kk][bb];
    }
  } else {
    const int d0 = (blk - 1024) * 64;
    for (int u = tid; u < 4096; u += 256) {
      int cc = u >> 6, dd = u & 63;
      tile[dd][cc] = fc_w[(unsigned)cc * 1024u + d0 + dd];
    }
    __syncthreads();
    for (int u = tid; u < 4096; u += 256) {
      int dd = u >> 6, cc = u & 63;
      ws[FCWT_F + (unsigned)(d0 + dd) * 64u + cc] = tile[dd][cc];
    }
  }
}

__launch_bounds__(256, 1)
__global__ void lstm_main(const float* __restrict__ W_ih, const float* __restrict__ W_hh,
                          const float* __restrict__ b_ih, const float* __restrict__ b_hh,
                          const float* __restrict__ w_t, float* __restrict__ ws) {
  __shared__ float score[T_N][B_N];   // 64 KB score history (per-WG copy)
  __shared__ float Wx[I_N][8];        // 8 KB
  __shared__ float Wh[H_N][8];        // 16 KB
  __shared__ float red[4][8][B_N];    // 8 KB gate partials per k-quarter
  __shared__ float psum[4][B_N];      // score-partial reduction
  __shared__ float cv[4][5][B_N];     // per-wave top-5 values
  __shared__ int   cj[4][4][B_N];     // per-wave top-4 indices
  __shared__ float cmn[4][B_N];       // per-wave min
  __shared__ float part[2][B_N];      // tanh(ho)*wt2 halves
  __shared__ float cst[2][B_N];       // LSTM c state
  __shared__ float bias[8];
  __shared__ float wt2[2];

  const int g = blockIdx.x;
  const int tid = threadIdx.x;
  const int b = tid & 63;
  const int kq = tid >> 6;

  unsigned int* bar = (unsigned int*)(ws + BAR_F);

  // stage weights (resident all steps)
  for (int idx = tid; idx < 8 * I_N; idx += 256) {
    int rr = idx >> 8, k = idx & (I_N - 1);
    int grow = (rr >> 1) * H_N + 2 * g + (rr & 1);   // rr = gate*2 + jj
    Wx[k][rr] = W_ih[grow * I_N + k];
  }
  for (int idx = tid; idx < 8 * H_N; idx += 256) {
    int rr = idx >> 9, k = idx & (H_N - 1);
    int grow = (rr >> 1) * H_N + 2 * g + (rr & 1);
    Wh[k][rr] = W_hh[grow * H_N + k];
  }
  if (tid < 8) {
    int grow = (tid >> 1) * H_N + 2 * g + (tid & 1);
    bias[tid] = b_ih[grow] + b_hh[grow];
  }
  if (tid < 2) wt2[tid] = w_t[H_N + 2 * g + tid];
  if (tid < 128) cst[tid >> 6][tid & 63] = 0.0f;
  __syncthreads();

  for (int i = 0; i < T_N; ++i) {
    // ---- Phase A: score-partial reduction + gate matvec (all 256 threads) ----
    float ps = 0.0f;
    {
      const float* pp = ws + PSUM_F + ((unsigned)(i + 1) & 1u) * 16384u
                        + (unsigned)(kq * 64) * 64u + b;
      #pragma unroll 8
      for (int j = 0; j < 64; ++j) ps += pp[j * 64];
    }
    psum[kq][b] = ps;

    float acc[8];
    #pragma unroll
    for (int r = 0; r < 8; ++r) acc[r] = 0.0f;
    {
      const float* xp = ws + XT_F + (unsigned)i * (I_N * B_N) + b;
      #pragma unroll 4
      for (int k = kq * 64; k < kq * 64 + 64; ++k) {
        float v = xp[k * 64];
        const float* wr = &Wx[k][0];
        #pragma unroll
        for (int r = 0; r < 8; ++r) acc[r] += v * wr[r];
      }
      const float* hp = ws + MEM_F + (unsigned)i * SLICE + b;  // mem[i] == h_out(i-1)
      #pragma unroll 4
      for (int k = kq * 128; k < kq * 128 + 128; ++k) {
        float v = hp[k * 64];
        const float* wr = &Wh[k][0];
        #pragma unroll
        for (int r = 0; r < 8; ++r) acc[r] += v * wr[r];
      }
    }
    #pragma unroll
    for (int r = 0; r < 8; ++r) red[kq][r][b] = acc[r];
    __syncthreads();  // S1

    // ---- Phase B: finalize score; distributed partial top-5 scan ----
    float sc = psum[0][b] + psum[1][b] + psum[2][b] + psum[3][b];
    if (tid < 64) score[i][tid] = sc;   // for future steps (t=i read via register now)
    {
      float v0 = -3e38f, v1 = -3e38f, v2 = -3e38f, v3 = -3e38f, v4 = -3e38f;
      int j0 = 0, j1 = 0, j2 = 0, j3 = 0;
      float mn = 3e38f;
      const int tlo = kq * 64;
      const int thi = (kq * 64 + 63 < i) ? kq * 64 + 63 : i;
      for (int t = tlo; t <= thi; ++t) {
        float s = (t == i) ? sc : score[t][b];
        mn = fminf(mn, s);
        ins5(s, t, v0, v1, v2, v3, v4, j0, j1, j2, j3);
      }
      cv[kq][0][b] = v0; cv[kq][1][b] = v1; cv[kq][2][b] = v2;
      cv[kq][3][b] = v3; cv[kq][4][b] = v4;
      cj[kq][0][b] = j0; cj[kq][1][b] = j1; cj[kq][2][b] = j2; cj[kq][3][b] = j3;
      cmn[kq][b] = mn;
    }
    __syncthreads();  // S2

    // ---- Phase C+D (tid<128): merge top-5, weights, LSTM cell, gather, writes ----
    if (tid < 128) {
      float v0 = -3e38f, v1 = -3e38f, v2 = -3e38f, v3 = -3e38f, v4 = -3e38f;
      int j0 = 0, j1 = 0, j2 = 0, j3 = 0;
      float mn = 3e38f;
      #pragma unroll
      for (int q = 0; q < 4; ++q) {
        mn = fminf(mn, cmn[q][b]);
        ins5(cv[q][0][b], cj[q][0][b], v0, v1, v2, v3, v4, j0, j1, j2, j3);
        ins5(cv[q][1][b], cj[q][1][b], v0, v1, v2, v3, v4, j0, j1, j2, j3);
        ins5(cv[q][2][b], cj[q][2][b], v0, v1, v2, v3, v4, j0, j1, j2, j3);
        ins5(cv[q][3][b], cj[q][3][b], v0, v1, v2, v3, v4, j0, j1, j2, j3);
        ins5(cv[q][4][b], 0,           v0, v1, v2, v3, v4, j0, j1, j2, j3);  // value-only (rank>=5)
      }
      float delta = ((i + 1) <= 5 ? mn : v4) + EPSF;
      float w0 = fmaxf(v0 - delta, 0.0f);
      float w1 = fmaxf(v1 - delta, 0.0f);
      float w2 = fmaxf(v2 - delta, 0.0f);
      float w3 = fmaxf(v3 - delta, 0.0f);
      float inv = 1.0f / (w0 + w1 + w2 + w3 + EPSF);
      w0 *= inv; w1 *= inv; w2 *= inv; w3 *= inv;

      const int jj = tid >> 6;
      float gi = red[0][  jj][b] + red[1][  jj][b] + red[2][  jj][b] + red[3][  jj][b] + bias[  jj];
      float gf = red[0][2+jj][b] + red[1][2+jj][b] + red[2][2+jj][b] + red[3][2+jj][b] + bias[2+jj];
      float gg = red[0][4+jj][b] + red[1][4+jj][b] + red[2][4+jj][b] + red[3][4+jj][b] + bias[4+jj];
      float go = red[0][6+jj][b] + red[1][6+jj][b] + red[2][6+jj][b] + red[3][6+jj][b] + bias[6+jj];
      float cn = sigf(gf) * cst[jj][b] + sigf(gi) * tanhf(gg);
      float hn = sigf(go) * tanhf(cn);
      cst[jj][b] = cn;

      const float* mb = ws + MEM_F + (unsigned)(2 * g + jj) * 64u + b;
      float m = w0 * mb[(unsigned)j0 * SLICE] + w1 * mb[(unsigned)j1 * SLICE]
              + w2 * mb[(unsigned)j2 * SLICE] + w3 * mb[(unsigned)j3 * SLICE];
      float ho = hn + m;
      ws[MEM_F  + (unsigned)(i + 1) * SLICE + (unsigned)(2 * g + jj) * 64u + b] = ho;
      ws[MSEQ_F + (unsigned)i       * SLICE + (unsigned)(2 * g + jj) * 64u + b] = m;
      part[jj][b] = tanhf(ho) * wt2[jj];
    }
    __syncthreads();  // S3

    // ---- Phase E: publish score partial; grid barrier ----
    if (tid < 64) {
      ws[PSUM_F + ((unsigned)i & 1u) * 16384u + (unsigned)g * 64u + tid]
          = part[0][tid] + part[1][tid];
    }
    if (tid == 0) {
      __threadfence();  // release: own P write (vmcnt) + wbL2 of block's mem/mseq writes
      __hip_atomic_fetch_add(bar, 1u, __ATOMIC_RELAXED, __HIP_MEMORY_SCOPE_AGENT);
      const unsigned int tgt = (unsigned)(i + 1) * 256u;
      while (__hip_atomic_load(bar, __ATOMIC_RELAXED, __HIP_MEMORY_SCOPE_AGENT) < tgt) {
        __builtin_amdgcn_s_sleep(2);
      }
      __threadfence();  // acquire: invalidate CU L1 + XCD L2 stale lines
    }
    __syncthreads();  // S4
  }
}

// out[t,b,c] = sum_d feats[t,d,b]*fcwT[d,c] + fc_b[c];
// feats h-half == mem[t+1], m-half == mseq[t]. Block = (t, c-group of 16).
__launch_bounds__(256)
__global__ void out_gemm(const float* __restrict__ ws, const float* __restrict__ fc_b,
                         float* __restrict__ out) {
  __shared__ float fw[64][16];
  const int t = blockIdx.x >> 2, cg = blockIdx.x & 3;
  const int tid = threadIdx.x, b = tid & 63, cs = (tid >> 6) * 4;
  float acc[4] = {0.0f, 0.0f, 0.0f, 0.0f};
  const float* hsrc = ws + MEM_F + (unsigned)(t + 1) * SLICE + b;
  const float* msrc = ws + MSEQ_F + (unsigned)t * SLICE + b;
  for (int half = 0; half < 2; ++half) {
    const float* src = half ? msrc : hsrc;
    for (int dt = 0; dt < 512; dt += 64) {
      __syncthreads();
      for (int u = tid; u < 1024; u += 256) {
        int dd = u >> 4, cc = u & 15;
        fw[dd][cc] = ws[FCWT_F + (unsigned)(half * 512 + dt + dd) * 64u + cg * 16 + cc];
      }
      __syncthreads();
      for (int dd = 0; dd < 64; ++dd) {
        float f = src[(unsigned)(dt + dd) * 64u];
        #pragma unroll
        for (int c4 = 0; c4 < 4; ++c4) acc[c4] += f * fw[dd][cs + c4];
      }
    }
  }
  float* op = out + ((unsigned)t * 64u + b) * 64u + cg * 16 + cs;
  #pragma unroll
  for (int c4 = 0; c4 < 4; ++c4) op[c4] = acc[c4] + fc_b[cg * 16 + cs + c4];
}

extern "C" void kernel_launch(void* const* d_in, const int* in_sizes, int n_in,
                              void* d_out, int out_size, void* d_ws, size_t ws_size,
                              hipStream_t stream) {
  const float* x    = (const float*)d_in[0];
  const float* W_ih = (const float*)d_in[1];
  const float* W_hh = (const float*)d_in[2];
  const float* b_ih = (const float*)d_in[3];
  const float* b_hh = (const float*)d_in[4];
  const float* w_t  = (const float*)d_in[5];
  const float* fc_w = (const float*)d_in[6];
  const float* fc_b = (const float*)d_in[7];
  float* out = (float*)d_out;
  float* ws  = (float*)d_ws;

  if (ws_size < (size_t)TOT_F * 4u) {
    poison_k<<<(out_size + 255) / 256, 256, 0, stream>>>(out, out_size);
    return;
  }

  hipMemsetAsync(ws + MEM_F, 0, (size_t)SLICE * 4u, stream);            // mem[0] = 0
  hipMemsetAsync(ws + PSUM_F, 0, (size_t)32768u * 4u, stream);          // both P planes
  hipMemsetAsync(ws + BAR_F, 0, 16u, stream);                          // barrier

  init_k<<<1040, 256, 0, stream>>>(x, fc_w, ws);
  lstm_main<<<256, 256, 0, stream>>>(W_ih, W_hh, b_ih, b_hh, w_t, ws);
  out_gemm<<<1024, 256, 0, stream>>>(ws, fc_b, out);
}

// Round 3
// 7586.893 us; speedup vs baseline: 2.3060x; 2.3060x over previous
//
#include <hip/hip_runtime.h>

// ---------------------------------------------------------------------------
// self_LSTM_sparse_attn — MI355X persistent-kernel, round 3.
//
// R2 post-mortem: 256-way same-line atomic fetch_add barrier serialized at
// ~150ns/RMW => ~38us/step. Replaced with contention-free flag barrier:
//   arrival  = per-WG agent store to its own 64B line (parallel, no RMW)
//   collect  = WG0's 256 threads poll one flag each, then publish epoch
//   release  = 255 WGs read-poll epoch (reads don't serialize)
// Next step's x-part matvec overlaps the arrival/collect window.
//
// Algorithm (unchanged from R2, verified): s_h cancels in the attention
// weights => w depends only on cached s_mem; w is <=4-sparse; WG g owns h
// dims {2g,2g+1}, weights LDS-resident; mem[t][h][b] doubles as h broadcast.
// ---------------------------------------------------------------------------

#define T_N 256
#define B_N 64
#define I_N 256
#define H_N 512
#define C_N 64
#define EPSF 1e-7f
#define SLICE 32768u  // H_N*B_N floats per mem slice

// ws layout (float offsets)
#define XT_F    0u          // [T][I][B]   x transposed fp32     (4,194,304)
#define MEM_F   4194304u    // [T+1][H][B] h_out history         (8,421,376)
#define MSEQ_F  12615680u   // [T][H][B]   m_seq                 (8,388,608)
#define PSUM_F  21004288u   // [2][256][64] score partials       (32,768)
#define FCWT_F  21037056u   // [2H][C]     fc_w transposed       (65,536)
#define FLAG_F  21102592u   // [256] arrival flags, stride 16 u32 (4,096)
#define EPOCH_F 21106688u   // epoch counter                     (16)
#define TOT_F   21106704u

__device__ __forceinline__ float sigf(float x) { return 1.0f / (1.0f + expf(-x)); }

__device__ __forceinline__ void ins5(float s, int t,
                                     float& v0, float& v1, float& v2, float& v3, float& v4,
                                     int& j0, int& j1, int& j2, int& j3) {
  if (s > v4) {
    if (s > v0)      { v4=v3; v3=v2; j3=j2; v2=v1; j2=j1; v1=v0; j1=j0; v0=s; j0=t; }
    else if (s > v1) { v4=v3; v3=v2; j3=j2; v2=v1; j2=j1; v1=s; j1=t; }
    else if (s > v2) { v4=v3; v3=v2; j3=j2; v2=s; j2=t; }
    else if (s > v3) { v4=v3; v3=s; j3=t; }
    else             { v4=s; }
  }
}

__global__ void poison_k(float* out, int n) {
  int i = blockIdx.x * 256 + threadIdx.x;
  if (i < n) out[i] = __int_as_float(0x7fc00000);
}

// blocks 0..1023: transpose x -> xT[t][k][b]; blocks 1024..1039: fc_w -> fcwT[d][c]
__global__ void init_k(const float* __restrict__ x, const float* __restrict__ fc_w,
                       float* __restrict__ ws) {
  __shared__ float tile[64][65];
  const int blk = blockIdx.x, tid = threadIdx.x;
  if (blk < 1024) {
    const int t = blk >> 2, k0 = (blk & 3) * 64;
    for (int u = tid; u < 4096; u += 256) {
      int bb = u >> 6, kk = u & 63;
      tile[kk][bb] = x[((unsigned)t * 64u + bb) * 256u + k0 + kk];
    }
    __syncthreads();
    for (int u = tid; u < 4096; u += 256) {
      int kk = u >> 6, bb = u & 63;
      ws[XT_F + (unsigned)t * 16384u + (unsigned)(k0 + kk) * 64u + bb] = tile[kk][bb];
    }
  } else {
    const int d0 = (blk - 1024) * 64;
    for (int u = tid; u < 4096; u += 256) {
      int cc = u >> 6, dd = u & 63;
      tile[dd][cc] = fc_w[(unsigned)cc * 1024u + d0 + dd];
    }
    __syncthreads();
    for (int u = tid; u < 4096; u += 256) {
      int dd = u >> 6, cc = u & 63;
      ws[FCWT_F + (unsigned)(d0 + dd) * 64u + cc] = tile[dd][cc];
    }
  }
}

__launch_bounds__(256, 1)
__global__ void lstm_main(const float* __restrict__ W_ih, const float* __restrict__ W_hh,
                          const float* __restrict__ b_ih, const float* __restrict__ b_hh,
                          const float* __restrict__ w_t, float* __restrict__ ws) {
  __shared__ float score[T_N][B_N];   // 64 KB score history (per-WG copy)
  __shared__ float Wx[I_N][8];        // 8 KB
  __shared__ float Wh[H_N][8];        // 16 KB
  __shared__ float red[4][8][B_N];    // 8 KB gate partials per k-quarter
  __shared__ float psum[4][B_N];
  __shared__ float cv[4][5][B_N];     // per-wave top-5 values
  __shared__ int   cj[4][4][B_N];     // per-wave top-4 indices
  __shared__ float cmn[4][B_N];
  __shared__ float part[2][B_N];
  __shared__ float cst[2][B_N];
  __shared__ float bias[8];
  __shared__ float wt2[2];

  const int g = blockIdx.x;
  const int tid = threadIdx.x;
  const int b = tid & 63;
  const int kq = tid >> 6;

  unsigned int* flags = (unsigned int*)(ws + FLAG_F);
  unsigned int* epoch = (unsigned int*)(ws + EPOCH_F);

  // stage weights (resident all steps)
  for (int idx = tid; idx < 8 * I_N; idx += 256) {
    int rr = idx >> 8, k = idx & (I_N - 1);
    int grow = (rr >> 1) * H_N + 2 * g + (rr & 1);   // rr = gate*2 + jj
    Wx[k][rr] = W_ih[grow * I_N + k];
  }
  for (int idx = tid; idx < 8 * H_N; idx += 256) {
    int rr = idx >> 9, k = idx & (H_N - 1);
    int grow = (rr >> 1) * H_N + 2 * g + (rr & 1);
    Wh[k][rr] = W_hh[grow * H_N + k];
  }
  if (tid < 8) {
    int grow = (tid >> 1) * H_N + 2 * g + (tid & 1);
    bias[tid] = b_ih[grow] + b_hh[grow];
  }
  if (tid < 2) wt2[tid] = w_t[H_N + 2 * g + tid];
  if (tid < 128) cst[tid >> 6][tid & 63] = 0.0f;
  __syncthreads();

  // prologue: x-part of step 0's matvec
  float xacc[8];
  #pragma unroll
  for (int r = 0; r < 8; ++r) xacc[r] = 0.0f;
  {
    const float* xp = ws + XT_F + b;
    #pragma unroll 8
    for (int k = kq * 64; k < kq * 64 + 64; ++k) {
      float v = xp[k * 64];
      const float* wr = &Wx[k][0];
      #pragma unroll
      for (int r = 0; r < 8; ++r) xacc[r] += v * wr[r];
    }
  }

  for (int i = 0; i < T_N; ++i) {
    // ---- S0: wait for step i-1 to be globally complete ----
    if (i > 0) {
      if (g == 0) {
        // collector: 256 threads poll one flag each (parallel, read-only)
        while (__hip_atomic_load(&flags[tid << 4], __ATOMIC_RELAXED,
                                 __HIP_MEMORY_SCOPE_AGENT) < (unsigned)i)
          __builtin_amdgcn_s_sleep(1);
        __syncthreads();
        if (tid == 0) {
          __hip_atomic_store(epoch, (unsigned)i, __ATOMIC_RELAXED,
                             __HIP_MEMORY_SCOPE_AGENT);
          __builtin_amdgcn_fence(__ATOMIC_ACQUIRE, "agent");  // inv L1/L2
        }
      } else {
        if (tid == 0) {
          while (__hip_atomic_load(epoch, __ATOMIC_RELAXED,
                                   __HIP_MEMORY_SCOPE_AGENT) < (unsigned)i)
            __builtin_amdgcn_s_sleep(1);
          __builtin_amdgcn_fence(__ATOMIC_ACQUIRE, "agent");
        }
      }
      __syncthreads();
    }

    // ---- Phase A: score-partial reduction + h-part matvec ----
    float ps = 0.0f;
    {
      const float* pp = ws + PSUM_F + ((unsigned)(i + 1) & 1u) * 16384u
                        + (unsigned)(kq * 64) * 64u + b;
      #pragma unroll 8
      for (int j = 0; j < 64; ++j) ps += pp[j * 64];
    }
    psum[kq][b] = ps;

    float acc[8];
    #pragma unroll
    for (int r = 0; r < 8; ++r) acc[r] = xacc[r];
    {
      const float* hp = ws + MEM_F + (unsigned)i * SLICE + b;  // mem[i] == h_out(i-1)
      #pragma unroll 8
      for (int k = kq * 128; k < kq * 128 + 128; ++k) {
        float v = hp[k * 64];
        const float* wr = &Wh[k][0];
        #pragma unroll
        for (int r = 0; r < 8; ++r) acc[r] += v * wr[r];
      }
    }
    #pragma unroll
    for (int r = 0; r < 8; ++r) red[kq][r][b] = acc[r];
    __syncthreads();  // S1

    // ---- Phase B: finalize score; distributed partial top-5 scan ----
    float sc = psum[0][b] + psum[1][b] + psum[2][b] + psum[3][b];
    if (tid < 64) score[i][tid] = sc;
    {
      float v0 = -3e38f, v1 = -3e38f, v2 = -3e38f, v3 = -3e38f, v4 = -3e38f;
      int j0 = 0, j1 = 0, j2 = 0, j3 = 0;
      float mn = 3e38f;
      const int tlo = kq * 64;
      const int thi = (kq * 64 + 63 < i) ? kq * 64 + 63 : i;
      for (int t = tlo; t <= thi; ++t) {
        float s = (t == i) ? sc : score[t][b];
        mn = fminf(mn, s);
        ins5(s, t, v0, v1, v2, v3, v4, j0, j1, j2, j3);
      }
      cv[kq][0][b] = v0; cv[kq][1][b] = v1; cv[kq][2][b] = v2;
      cv[kq][3][b] = v3; cv[kq][4][b] = v4;
      cj[kq][0][b] = j0; cj[kq][1][b] = j1; cj[kq][2][b] = j2; cj[kq][3][b] = j3;
      cmn[kq][b] = mn;
    }
    __syncthreads();  // S2

    // ---- Phase C+D (tid<128): merge top-5, weights, LSTM cell, gather ----
    if (tid < 128) {
      float v0 = -3e38f, v1 = -3e38f, v2 = -3e38f, v3 = -3e38f, v4 = -3e38f;
      int j0 = 0, j1 = 0, j2 = 0, j3 = 0;
      float mn = 3e38f;
      #pragma unroll
      for (int q = 0; q < 4; ++q) {
        mn = fminf(mn, cmn[q][b]);
        ins5(cv[q][0][b], cj[q][0][b], v0, v1, v2, v3, v4, j0, j1, j2, j3);
        ins5(cv[q][1][b], cj[q][1][b], v0, v1, v2, v3, v4, j0, j1, j2, j3);
        ins5(cv[q][2][b], cj[q][2][b], v0, v1, v2, v3, v4, j0, j1, j2, j3);
        ins5(cv[q][3][b], cj[q][3][b], v0, v1, v2, v3, v4, j0, j1, j2, j3);
        ins5(cv[q][4][b], 0,           v0, v1, v2, v3, v4, j0, j1, j2, j3);  // rank>=5: value-only
      }
      float delta = ((i + 1) <= 5 ? mn : v4) + EPSF;
      float w0 = fmaxf(v0 - delta, 0.0f);
      float w1 = fmaxf(v1 - delta, 0.0f);
      float w2 = fmaxf(v2 - delta, 0.0f);
      float w3 = fmaxf(v3 - delta, 0.0f);
      float inv = 1.0f / (w0 + w1 + w2 + w3 + EPSF);
      w0 *= inv; w1 *= inv; w2 *= inv; w3 *= inv;

      const int jj = tid >> 6;
      float gi = red[0][  jj][b] + red[1][  jj][b] + red[2][  jj][b] + red[3][  jj][b] + bias[  jj];
      float gf = red[0][2+jj][b] + red[1][2+jj][b] + red[2][2+jj][b] + red[3][2+jj][b] + bias[2+jj];
      float gg = red[0][4+jj][b] + red[1][4+jj][b] + red[2][4+jj][b] + red[3][4+jj][b] + bias[4+jj];
      float go = red[0][6+jj][b] + red[1][6+jj][b] + red[2][6+jj][b] + red[3][6+jj][b] + bias[6+jj];
      float cn = sigf(gf) * cst[jj][b] + sigf(gi) * tanhf(gg);
      float hn = sigf(go) * tanhf(cn);
      cst[jj][b] = cn;

      const float* mb = ws + MEM_F + (unsigned)(2 * g + jj) * 64u + b;
      float m = w0 * mb[(unsigned)j0 * SLICE] + w1 * mb[(unsigned)j1 * SLICE]
              + w2 * mb[(unsigned)j2 * SLICE] + w3 * mb[(unsigned)j3 * SLICE];
      float ho = hn + m;
      ws[MEM_F  + (unsigned)(i + 1) * SLICE + (unsigned)(2 * g + jj) * 64u + b] = ho;
      ws[MSEQ_F + (unsigned)i       * SLICE + (unsigned)(2 * g + jj) * 64u + b] = m;
      part[jj][b] = tanhf(ho) * wt2[jj];
    }
    __syncthreads();  // S3

    // ---- Phase E: publish score partial; signal arrival (no RMW!) ----
    if (tid < 64) {
      ws[PSUM_F + ((unsigned)i & 1u) * 16384u + (unsigned)g * 64u + tid]
          = part[0][tid] + part[1][tid];
    }
    if (tid == 0) {
      __builtin_amdgcn_fence(__ATOMIC_RELEASE, "agent");  // wbl2: push writes to LIC
      __hip_atomic_store(&flags[g << 4], (unsigned)(i + 1), __ATOMIC_RELAXED,
                         __HIP_MEMORY_SCOPE_AGENT);
    }

    // ---- overlap: x-part of NEXT step's matvec (static xT, no dependency) ----
    if (i + 1 < T_N) {
      #pragma unroll
      for (int r = 0; r < 8; ++r) xacc[r] = 0.0f;
      const float* xp = ws + XT_F + (unsigned)(i + 1) * (I_N * B_N) + b;
      #pragma unroll 8
      for (int k = kq * 64; k < kq * 64 + 64; ++k) {
        float v = xp[k * 64];
        const float* wr = &Wx[k][0];
        #pragma unroll
        for (int r = 0; r < 8; ++r) xacc[r] += v * wr[r];
      }
    }
  }
}

// out[t,b,c] = sum_d feats[t,d,b]*fcwT[d,c] + fc_b[c];
// feats h-half == mem[t+1], m-half == mseq[t]. Block = (t, c-group of 16).
__launch_bounds__(256, 4)
__global__ void out_gemm(const float* __restrict__ ws, const float* __restrict__ fc_b,
                         float* __restrict__ out) {
  __shared__ float fw[64][16];
  const int t = blockIdx.x >> 2, cg = blockIdx.x & 3;
  const int tid = threadIdx.x, b = tid & 63, cs = (tid >> 6) * 4;
  float acc[4] = {0.0f, 0.0f, 0.0f, 0.0f};
  const float* hsrc = ws + MEM_F + (unsigned)(t + 1) * SLICE + b;
  const float* msrc = ws + MSEQ_F + (unsigned)t * SLICE + b;
  for (int half = 0; half < 2; ++half) {
    const float* src = half ? msrc : hsrc;
    for (int dt = 0; dt < 512; dt += 64) {
      __syncthreads();
      for (int u = tid; u < 1024; u += 256) {
        int dd = u >> 4, cc = u & 15;
        fw[dd][cc] = ws[FCWT_F + (unsigned)(half * 512 + dt + dd) * 64u + cg * 16 + cc];
      }
      __syncthreads();
      #pragma unroll 4
      for (int dd = 0; dd < 64; ++dd) {
        float f = src[(unsigned)(dt + dd) * 64u];
        #pragma unroll
        for (int c4 = 0; c4 < 4; ++c4) acc[c4] += f * fw[dd][cs + c4];
      }
    }
  }
  float* op = out + ((unsigned)t * 64u + b) * 64u + cg * 16 + cs;
  #pragma unroll
  for (int c4 = 0; c4 < 4; ++c4) op[c4] = acc[c4] + fc_b[cg * 16 + cs + c4];
}

extern "C" void kernel_launch(void* const* d_in, const int* in_sizes, int n_in,
                              void* d_out, int out_size, void* d_ws, size_t ws_size,
                              hipStream_t stream) {
  const float* x    = (const float*)d_in[0];
  const float* W_ih = (const float*)d_in[1];
  const float* W_hh = (const float*)d_in[2];
  const float* b_ih = (const float*)d_in[3];
  const float* b_hh = (const float*)d_in[4];
  const float* w_t  = (const float*)d_in[5];
  const float* fc_w = (const float*)d_in[6];
  const float* fc_b = (const float*)d_in[7];
  float* out = (float*)d_out;
  float* ws  = (float*)d_ws;

  if (ws_size < (size_t)TOT_F * 4u) {
    poison_k<<<(out_size + 255) / 256, 256, 0, stream>>>(out, out_size);
    return;
  }

  hipMemsetAsync(ws + MEM_F, 0, (size_t)SLICE * 4u, stream);      // mem[0] = 0
  hipMemsetAsync(ws + PSUM_F, 0, (size_t)32768u * 4u, stream);    // both P planes
  hipMemsetAsync(ws + FLAG_F, 0, (size_t)(TOT_F - FLAG_F) * 4u, stream);  // flags+epoch

  init_k<<<1040, 256, 0, stream>>>(x, fc_w, ws);
  lstm_main<<<256, 256, 0, stream>>>(W_ih, W_hh, b_ih, b_hh, w_t, ws);
  out_gemm<<<1024, 256, 0, stream>>>(ws, fc_b, out);
}

// Round 4
// 4731.751 us; speedup vs baseline: 3.6974x; 1.6034x over previous
//
#include <hip/hip_runtime.h>

// ---------------------------------------------------------------------------
// self_LSTM_sparse_attn — MI355X persistent-kernel, round 4.
//
// R3 post-mortem: 29.3us/step, VALUBusy 18%, 1 wave/SIMD -> latency-bound on
// ~256 scalar LIC loads/wave/step + O(i) top-5 rescan. This round:
//   (1) incremental top-5 (insertion-only维护): one ins5/step by the owner
//       wave; O(i) scan and the 64KB score LDS cache are gone.
//   (2) all cross-step streams repacked [..][k/4][b][4] -> dwordx4 loads.
//   (3) load-all-then-consume register arrays (48 loads in flight/wave).
//
// Algorithm (R2/R3-verified): s_h cancels in attention weights => w depends
// only on cached s_mem; w is <=4-sparse; WG g owns h dims {2g,2g+1}; weights
// LDS-resident; mem[i] doubles as h_out(i-1) broadcast; contention-free flag
// barrier (per-WG agent stores + WG0 collector + epoch release).
// ---------------------------------------------------------------------------

#define T_N 256
#define B_N 64
#define I_N 256
#define H_N 512
#define C_N 64
#define EPSF 1e-7f

typedef float v4f __attribute__((ext_vector_type(4)));

// ws layout (float offsets). Packed layouts: [..][k4][b][u] u=k&3.
#define XT4_F   0u          // [T][64][64][4]   x packed        (4,194,304)
#define MEM4_F  4194304u    // [T+1][128][64][4] h_out history  (8,421,376)
#define MSEQ4_F 12615680u   // [T][128][64][4]  m_seq           (8,388,608)
#define PSUM4_F 21004288u   // [2][64][64][4]   score partials  (32,768)
#define FCWT_F  21037056u   // [2H][C] fc_w transposed          (65,536)
#define FLAG_F  21102592u   // [256] arrival flags, stride 16 u32 (4,096)
#define EPOCH_F 21106688u   // epoch counter                    (16)
#define TOT_F   21106704u

__device__ __forceinline__ float sigf(float x) { return 1.0f / (1.0f + expf(-x)); }

__device__ __forceinline__ void ins5(float s, int t,
                                     float& v0, float& v1, float& v2, float& v3, float& v4,
                                     int& j0, int& j1, int& j2, int& j3) {
  if (s > v4) {
    if (s > v0)      { v4=v3; v3=v2; j3=j2; v2=v1; j2=j1; v1=v0; j1=j0; v0=s; j0=t; }
    else if (s > v1) { v4=v3; v3=v2; j3=j2; v2=v1; j2=j1; v1=s; j1=t; }
    else if (s > v2) { v4=v3; v3=v2; j3=j2; v2=s; j2=t; }
    else if (s > v3) { v4=v3; v3=s; j3=t; }
    else             { v4=s; }
  }
}

__global__ void poison_k(float* out, int n) {
  int i = blockIdx.x * 256 + threadIdx.x;
  if (i < n) out[i] = __int_as_float(0x7fc00000);
}

// blocks 0..1023: x -> xT4 packed; blocks 1024..1039: fc_w -> fcwT[d][c]
__global__ void init_k(const float* __restrict__ x, const float* __restrict__ fc_w,
                       float* __restrict__ ws) {
  __shared__ float tile[64][65];
  const int blk = blockIdx.x, tid = threadIdx.x;
  if (blk < 1024) {
    const int t = blk >> 2, k0 = (blk & 3) * 64;
    for (int u = tid; u < 4096; u += 256) {
      int bb = u >> 6, kk = u & 63;
      tile[kk][bb] = x[((unsigned)t * 64u + bb) * 256u + k0 + kk];
    }
    __syncthreads();
    for (int u = tid; u < 4096; u += 256) {
      int kk = u >> 6, bb = u & 63;
      int k = k0 + kk;
      ws[XT4_F + (unsigned)t * 16384u + (unsigned)(k >> 2) * 256u
         + (unsigned)bb * 4u + (unsigned)(k & 3)] = tile[kk][bb];
    }
  } else {
    const int d0 = (blk - 1024) * 64;
    for (int u = tid; u < 4096; u += 256) {
      int cc = u >> 6, dd = u & 63;
      tile[dd][cc] = fc_w[(unsigned)cc * 1024u + d0 + dd];
    }
    __syncthreads();
    for (int u = tid; u < 4096; u += 256) {
      int dd = u >> 6, cc = u & 63;
      ws[FCWT_F + (unsigned)(d0 + dd) * 64u + cc] = tile[dd][cc];
    }
  }
}

__launch_bounds__(256, 1)
__global__ void lstm_main(const float* __restrict__ W_ih, const float* __restrict__ W_hh,
                          const float* __restrict__ b_ih, const float* __restrict__ b_hh,
                          const float* __restrict__ w_t, float* __restrict__ ws) {
  __shared__ float Wx[I_N][8];        // 8 KB
  __shared__ float Wh[H_N][8];        // 16 KB
  __shared__ float red[4][8][B_N];    // 8 KB gate partials per k-quarter
  __shared__ float psum[4][B_N];      // 1 KB
  __shared__ float cv[4][5][B_N];     // 5 KB  persistent running top-5 values
  __shared__ int   cj[4][4][B_N];     // 4 KB  persistent running top-4 indices
  __shared__ float cmn[4][B_N];       // 1 KB  persistent running min
  __shared__ float part[2][B_N];
  __shared__ float cst[2][B_N];
  __shared__ float bias[8];
  __shared__ float wt2[2];

  const int g = blockIdx.x;
  const int tid = threadIdx.x;
  const int b = tid & 63;
  const int kq = tid >> 6;

  unsigned int* flags = (unsigned int*)(ws + FLAG_F);
  unsigned int* epoch = (unsigned int*)(ws + EPOCH_F);

  // stage weights (resident all steps)
  for (int idx = tid; idx < 8 * I_N; idx += 256) {
    int rr = idx >> 8, k = idx & (I_N - 1);
    int grow = (rr >> 1) * H_N + 2 * g + (rr & 1);   // rr = gate*2 + jj
    Wx[k][rr] = W_ih[grow * I_N + k];
  }
  for (int idx = tid; idx < 8 * H_N; idx += 256) {
    int rr = idx >> 9, k = idx & (H_N - 1);
    int grow = (rr >> 1) * H_N + 2 * g + (rr & 1);
    Wh[k][rr] = W_hh[grow * H_N + k];
  }
  if (tid < 8) {
    int grow = (tid >> 1) * H_N + 2 * g + (tid & 1);
    bias[tid] = b_ih[grow] + b_hh[grow];
  }
  if (tid < 2) wt2[tid] = w_t[H_N + 2 * g + tid];
  if (tid < 128) cst[tid >> 6][tid & 63] = 0.0f;
  {  // init persistent running top-5 state: (q = tid>>6, b)
    cv[kq][0][b] = -3e38f; cv[kq][1][b] = -3e38f; cv[kq][2][b] = -3e38f;
    cv[kq][3][b] = -3e38f; cv[kq][4][b] = -3e38f;
    cj[kq][0][b] = 0; cj[kq][1][b] = 0; cj[kq][2][b] = 0; cj[kq][3][b] = 0;
    cmn[kq][b] = 3e38f;
  }
  __syncthreads();

  // prologue: x-part of step 0's matvec
  float xacc[8];
  #pragma unroll
  for (int r = 0; r < 8; ++r) xacc[r] = 0.0f;
  {
    const v4f* xp = (const v4f*)(ws + XT4_F) + b;
    v4f xv[16];
    #pragma unroll
    for (int j = 0; j < 16; ++j) xv[j] = xp[(kq * 16 + j) * 64];
    #pragma unroll
    for (int j = 0; j < 16; ++j) {
      #pragma unroll
      for (int u = 0; u < 4; ++u) {
        float v = xv[j][u];
        const float* wr = &Wx[4 * (kq * 16 + j) + u][0];
        #pragma unroll
        for (int r = 0; r < 8; ++r) xacc[r] += v * wr[r];
      }
    }
  }

  for (int i = 0; i < T_N; ++i) {
    // ---- S0: wait for step i-1 to be globally complete ----
    if (i > 0) {
      if (g == 0) {
        while (__hip_atomic_load(&flags[tid << 4], __ATOMIC_RELAXED,
                                 __HIP_MEMORY_SCOPE_AGENT) < (unsigned)i)
          __builtin_amdgcn_s_sleep(1);
        __syncthreads();
        if (tid == 0) {
          __hip_atomic_store(epoch, (unsigned)i, __ATOMIC_RELAXED,
                             __HIP_MEMORY_SCOPE_AGENT);
          __builtin_amdgcn_fence(__ATOMIC_ACQUIRE, "agent");
        }
      } else {
        if (tid == 0) {
          while (__hip_atomic_load(epoch, __ATOMIC_RELAXED,
                                   __HIP_MEMORY_SCOPE_AGENT) < (unsigned)i)
            __builtin_amdgcn_s_sleep(1);
          __builtin_amdgcn_fence(__ATOMIC_ACQUIRE, "agent");
        }
      }
      __syncthreads();
    }

    // ---- Phase A: issue all loads (psum first, h second), then consume ----
    v4f pv[16];
    {
      const v4f* pp = (const v4f*)(ws + PSUM4_F + ((unsigned)(i + 1) & 1u) * 16384u) + b;
      #pragma unroll
      for (int j = 0; j < 16; ++j) pv[j] = pp[(kq * 16 + j) * 64];
    }
    v4f hv[32];
    {
      const v4f* hp = (const v4f*)(ws + MEM4_F) + (unsigned)i * 8192u + b;  // mem[i] == h_out(i-1)
      #pragma unroll
      for (int j = 0; j < 32; ++j) hv[j] = hp[(kq * 32 + j) * 64];
    }
    float ps = 0.0f;
    #pragma unroll
    for (int j = 0; j < 16; ++j) ps += (pv[j][0] + pv[j][1]) + (pv[j][2] + pv[j][3]);
    psum[kq][b] = ps;

    float acc[8];
    #pragma unroll
    for (int r = 0; r < 8; ++r) acc[r] = xacc[r];
    #pragma unroll
    for (int j = 0; j < 32; ++j) {
      #pragma unroll
      for (int u = 0; u < 4; ++u) {
        float v = hv[j][u];
        const float* wr = &Wh[4 * (kq * 32 + j) + u][0];
        #pragma unroll
        for (int r = 0; r < 8; ++r) acc[r] += v * wr[r];
      }
    }
    #pragma unroll
    for (int r = 0; r < 8; ++r) red[kq][r][b] = acc[r];
    __syncthreads();  // S1

    // ---- Phase B: owner wave inserts t=i into its running top-5 ----
    if (kq == (i >> 6)) {
      float sc = psum[0][b] + psum[1][b] + psum[2][b] + psum[3][b];
      float v0 = cv[kq][0][b], v1 = cv[kq][1][b], v2 = cv[kq][2][b],
            v3 = cv[kq][3][b], v4 = cv[kq][4][b];
      int j0 = cj[kq][0][b], j1 = cj[kq][1][b], j2 = cj[kq][2][b], j3 = cj[kq][3][b];
      ins5(sc, i, v0, v1, v2, v3, v4, j0, j1, j2, j3);
      cv[kq][0][b] = v0; cv[kq][1][b] = v1; cv[kq][2][b] = v2;
      cv[kq][3][b] = v3; cv[kq][4][b] = v4;
      cj[kq][0][b] = j0; cj[kq][1][b] = j1; cj[kq][2][b] = j2; cj[kq][3][b] = j3;
      cmn[kq][b] = fminf(cmn[kq][b], sc);
    }
    __syncthreads();  // S2

    // ---- Phase C+D (tid<128): merge top-5, weights, LSTM cell, gather ----
    if (tid < 128) {
      float v0 = -3e38f, v1 = -3e38f, v2 = -3e38f, v3 = -3e38f, v4 = -3e38f;
      int j0 = 0, j1 = 0, j2 = 0, j3 = 0;
      float mn = 3e38f;
      #pragma unroll
      for (int q = 0; q < 4; ++q) {
        mn = fminf(mn, cmn[q][b]);
        ins5(cv[q][0][b], cj[q][0][b], v0, v1, v2, v3, v4, j0, j1, j2, j3);
        ins5(cv[q][1][b], cj[q][1][b], v0, v1, v2, v3, v4, j0, j1, j2, j3);
        ins5(cv[q][2][b], cj[q][2][b], v0, v1, v2, v3, v4, j0, j1, j2, j3);
        ins5(cv[q][3][b], cj[q][3][b], v0, v1, v2, v3, v4, j0, j1, j2, j3);
        ins5(cv[q][4][b], 0,           v0, v1, v2, v3, v4, j0, j1, j2, j3);  // rank>=5: value-only
      }
      float delta = ((i + 1) <= 5 ? mn : v4) + EPSF;
      float w0 = fmaxf(v0 - delta, 0.0f);
      float w1 = fmaxf(v1 - delta, 0.0f);
      float w2 = fmaxf(v2 - delta, 0.0f);
      float w3 = fmaxf(v3 - delta, 0.0f);
      float inv = 1.0f / (w0 + w1 + w2 + w3 + EPSF);
      w0 *= inv; w1 *= inv; w2 *= inv; w3 *= inv;

      const int jj = tid >> 6;
      float gi = red[0][  jj][b] + red[1][  jj][b] + red[2][  jj][b] + red[3][  jj][b] + bias[  jj];
      float gf = red[0][2+jj][b] + red[1][2+jj][b] + red[2][2+jj][b] + red[3][2+jj][b] + bias[2+jj];
      float gg = red[0][4+jj][b] + red[1][4+jj][b] + red[2][4+jj][b] + red[3][4+jj][b] + bias[4+jj];
      float go = red[0][6+jj][b] + red[1][6+jj][b] + red[2][6+jj][b] + red[3][6+jj][b] + bias[6+jj];
      float cn = sigf(gf) * cst[jj][b] + sigf(gi) * tanhf(gg);
      float hn = sigf(go) * tanhf(cn);
      cst[jj][b] = cn;

      const int hd = 2 * g + jj;
      const unsigned hoff = (unsigned)(hd >> 2) * 256u + (unsigned)b * 4u + (unsigned)(hd & 3);
      const float* mb = ws + MEM4_F + hoff;
      float m = w0 * mb[(unsigned)j0 * 32768u] + w1 * mb[(unsigned)j1 * 32768u]
              + w2 * mb[(unsigned)j2 * 32768u] + w3 * mb[(unsigned)j3 * 32768u];
      float ho = hn + m;
      ws[MEM4_F  + (unsigned)(i + 1) * 32768u + hoff] = ho;
      ws[MSEQ4_F + (unsigned)i       * 32768u + hoff] = m;
      part[jj][b] = tanhf(ho) * wt2[jj];
    }
    __syncthreads();  // S3

    // ---- Phase E: publish score partial; signal arrival (no RMW) ----
    if (tid < 64) {
      ws[PSUM4_F + ((unsigned)i & 1u) * 16384u + (unsigned)(g >> 2) * 256u
         + (unsigned)tid * 4u + (unsigned)(g & 3)] = part[0][tid] + part[1][tid];
    }
    if (tid == 0) {
      __builtin_amdgcn_fence(__ATOMIC_RELEASE, "agent");  // push writes toward LIC
      __hip_atomic_store(&flags[g << 4], (unsigned)(i + 1), __ATOMIC_RELAXED,
                         __HIP_MEMORY_SCOPE_AGENT);
    }

    // ---- overlap: x-part of NEXT step's matvec (static xT4, no dependency) ----
    if (i + 1 < T_N) {
      const v4f* xp = (const v4f*)(ws + XT4_F) + (unsigned)(i + 1) * 4096u + b;
      v4f xv[16];
      #pragma unroll
      for (int j = 0; j < 16; ++j) xv[j] = xp[(kq * 16 + j) * 64];
      #pragma unroll
      for (int r = 0; r < 8; ++r) xacc[r] = 0.0f;
      #pragma unroll
      for (int j = 0; j < 16; ++j) {
        #pragma unroll
        for (int u = 0; u < 4; ++u) {
          float v = xv[j][u];
          const float* wr = &Wx[4 * (kq * 16 + j) + u][0];
          #pragma unroll
          for (int r = 0; r < 8; ++r) xacc[r] += v * wr[r];
        }
      }
    }
  }
}

// out[t,b,c] = sum_d feats[t,d,b]*fcwT[d,c] + fc_b[c];
// feats h-half == mem4[t+1], m-half == mseq4[t] (packed [k4][b][4]).
__launch_bounds__(256, 4)
__global__ void out_gemm(const float* __restrict__ ws, const float* __restrict__ fc_b,
                         float* __restrict__ out) {
  __shared__ float fw[64][16];
  const int t = blockIdx.x >> 2, cg = blockIdx.x & 3;
  const int tid = threadIdx.x, b = tid & 63, cs = (tid >> 6) * 4;
  float acc[4] = {0.0f, 0.0f, 0.0f, 0.0f};
  const v4f* hsrc = (const v4f*)(ws + MEM4_F) + (unsigned)(t + 1) * 8192u + b;
  const v4f* msrc = (const v4f*)(ws + MSEQ4_F) + (unsigned)t * 8192u + b;
  for (int half = 0; half < 2; ++half) {
    const v4f* src = half ? msrc : hsrc;
    for (int dt = 0; dt < 512; dt += 64) {
      __syncthreads();
      for (int u = tid; u < 1024; u += 256) {
        int dd = u >> 4, cc = u & 15;
        fw[dd][cc] = ws[FCWT_F + (unsigned)(half * 512 + dt + dd) * 64u + cg * 16 + cc];
      }
      __syncthreads();
      #pragma unroll 4
      for (int j = 0; j < 16; ++j) {
        v4f f4 = src[(unsigned)(dt / 4 + j) * 64u];
        #pragma unroll
        for (int u = 0; u < 4; ++u) {
          float f = f4[u];
          const float* wr = &fw[4 * j + u][cs];
          #pragma unroll
          for (int c4 = 0; c4 < 4; ++c4) acc[c4] += f * wr[c4];
        }
      }
    }
  }
  float* op = out + ((unsigned)t * 64u + b) * 64u + cg * 16 + cs;
  #pragma unroll
  for (int c4 = 0; c4 < 4; ++c4) op[c4] = acc[c4] + fc_b[cg * 16 + cs + c4];
}

extern "C" void kernel_launch(void* const* d_in, const int* in_sizes, int n_in,
                              void* d_out, int out_size, void* d_ws, size_t ws_size,
                              hipStream_t stream) {
  const float* x    = (const float*)d_in[0];
  const float* W_ih = (const float*)d_in[1];
  const float* W_hh = (const float*)d_in[2];
  const float* b_ih = (const float*)d_in[3];
  const float* b_hh = (const float*)d_in[4];
  const float* w_t  = (const float*)d_in[5];
  const float* fc_w = (const float*)d_in[6];
  const float* fc_b = (const float*)d_in[7];
  float* out = (float*)d_out;
  float* ws  = (float*)d_ws;

  if (ws_size < (size_t)TOT_F * 4u) {
    poison_k<<<(out_size + 255) / 256, 256, 0, stream>>>(out, out_size);
    return;
  }

  hipMemsetAsync(ws + MEM4_F, 0, (size_t)32768u * 4u, stream);     // mem[0] = 0
  hipMemsetAsync(ws + PSUM4_F, 0, (size_t)32768u * 4u, stream);    // both P planes
  hipMemsetAsync(ws + FLAG_F, 0, (size_t)(TOT_F - FLAG_F) * 4u, stream);  // flags+epoch

  init_k<<<1040, 256, 0, stream>>>(x, fc_w, ws);
  lstm_main<<<256, 256, 0, stream>>>(W_ih, W_hh, b_ih, b_hh, w_t, ws);
  out_gemm<<<1024, 256, 0, stream>>>(ws, fc_b, out);
}

// Round 5
// 3042.602 us; speedup vs baseline: 5.7501x; 1.5552x over previous
//
#include <hip/hip_runtime.h>

// ---------------------------------------------------------------------------
// self_LSTM_sparse_attn — MI355X persistent-kernel, round 5.
//
// R4 post-mortem: 18.4us/step with 3us VALU -> the per-step agent fences
// (buffer_wbl2 + L2 inv walks, 256 WGs x 2 walks/step) dominate. This round
// eliminates ALL fences:
//   - every cross-WG datum is WRITE-ONCE within the dispatch (psum now has
//     one plane per step instead of double-buffer),
//   - cross-WG writes go straight to the LIC coherence point via
//     global_store sc0 sc1 (inline asm), so no wbl2 is needed,
//   - readers use plain cached loads: a line can only enter an L2 AFTER its
//     unique write (clean miss -> LIC -> valid), so no inv is needed,
//   - flag/epoch polls use sc0 sc1 loads (bypass L1/L2, read LIC).
// Store->flag ordering: __syncthreads drains vmcnt(0) per wave before
// s_barrier; explicit s_waitcnt vmcnt(0) before the flag store.
//
// Algorithm (verified R2-R4): s_h cancels in attention weights; w <=4-sparse;
// WG g owns h dims {2g,2g+1}; weights LDS-resident; mem[i] == h_out(i-1);
// incremental per-wave top-5 + merge; flag barrier with WG0 collector.
// ---------------------------------------------------------------------------

#define T_N 256
#define B_N 64
#define I_N 256
#define H_N 512
#define C_N 64
#define EPSF 1e-7f

typedef float v4f __attribute__((ext_vector_type(4)));

// ws layout (float offsets). Packed layouts: [..][k4][b][u] u=k&3.
#define XT4_F   0u          // [T][64][64][4]    x packed          (4,194,304)
#define MEM4_F  4194304u    // [T+1][128][64][4] h_out history     (8,421,376)
#define MSEQ4_F 12615680u   // [T][128][64][4]   m_seq             (8,388,608)
#define PSUM4_F 21004288u   // [T+1][64][64][4]  score partials, write-once (4,210,688)
#define FCWT_F  25214976u   // [2H][C] fc_w transposed             (65,536)
#define FLAG_F  25280512u   // [256] arrival flags, stride 16 u32  (4,096)
#define EPOCH_F 25284608u   // epoch counter                       (16)
#define TOT_F   25284624u

__device__ __forceinline__ float sigf(float x) { return 1.0f / (1.0f + expf(-x)); }

// direct-to-LIC (coherence point) ops — no fences needed anywhere.
__device__ __forceinline__ void st_lic_f32(float* p, float v) {
  asm volatile("global_store_dword %0, %1, off sc0 sc1" :: "v"(p), "v"(v) : "memory");
}
__device__ __forceinline__ void st_lic_u32(unsigned* p, unsigned v) {
  asm volatile("global_store_dword %0, %1, off sc0 sc1" :: "v"(p), "v"(v) : "memory");
}
__device__ __forceinline__ unsigned ld_lic_u32(const unsigned* p) {
  unsigned r;
  asm volatile("global_load_dword %0, %1, off sc0 sc1\n\ts_waitcnt vmcnt(0)"
               : "=v"(r) : "v"(p) : "memory");
  return r;
}

__device__ __forceinline__ void ins5(float s, int t,
                                     float& v0, float& v1, float& v2, float& v3, float& v4,
                                     int& j0, int& j1, int& j2, int& j3) {
  if (s > v4) {
    if (s > v0)      { v4=v3; v3=v2; j3=j2; v2=v1; j2=j1; v1=v0; j1=j0; v0=s; j0=t; }
    else if (s > v1) { v4=v3; v3=v2; j3=j2; v2=v1; j2=j1; v1=s; j1=t; }
    else if (s > v2) { v4=v3; v3=v2; j3=j2; v2=s; j2=t; }
    else if (s > v3) { v4=v3; v3=s; j3=t; }
    else             { v4=s; }
  }
}

__global__ void poison_k(float* out, int n) {
  int i = blockIdx.x * 256 + threadIdx.x;
  if (i < n) out[i] = __int_as_float(0x7fc00000);
}

// blocks 0..1023: x -> xT4 packed; blocks 1024..1039: fc_w -> fcwT[d][c]
__global__ void init_k(const float* __restrict__ x, const float* __restrict__ fc_w,
                       float* __restrict__ ws) {
  __shared__ float tile[64][65];
  const int blk = blockIdx.x, tid = threadIdx.x;
  if (blk < 1024) {
    const int t = blk >> 2, k0 = (blk & 3) * 64;
    for (int u = tid; u < 4096; u += 256) {
      int bb = u >> 6, kk = u & 63;
      tile[kk][bb] = x[((unsigned)t * 64u + bb) * 256u + k0 + kk];
    }
    __syncthreads();
    for (int u = tid; u < 4096; u += 256) {
      int kk = u >> 6, bb = u & 63;
      int k = k0 + kk;
      ws[XT4_F + (unsigned)t * 16384u + (unsigned)(k >> 2) * 256u
         + (unsigned)bb * 4u + (unsigned)(k & 3)] = tile[kk][bb];
    }
  } else {
    const int d0 = (blk - 1024) * 64;
    for (int u = tid; u < 4096; u += 256) {
      int cc = u >> 6, dd = u & 63;
      tile[dd][cc] = fc_w[(unsigned)cc * 1024u + d0 + dd];
    }
    __syncthreads();
    for (int u = tid; u < 4096; u += 256) {
      int dd = u >> 6, cc = u & 63;
      ws[FCWT_F + (unsigned)(d0 + dd) * 64u + cc] = tile[dd][cc];
    }
  }
}

__launch_bounds__(256, 1)
__global__ void lstm_main(const float* __restrict__ W_ih, const float* __restrict__ W_hh,
                          const float* __restrict__ b_ih, const float* __restrict__ b_hh,
                          const float* __restrict__ w_t, float* __restrict__ ws) {
  __shared__ float Wx[I_N][8];        // 8 KB
  __shared__ float Wh[H_N][8];        // 16 KB
  __shared__ float red[4][8][B_N];    // 8 KB gate partials per k-quarter
  __shared__ float psum[4][B_N];      // 1 KB
  __shared__ float cv[4][5][B_N];     // persistent running top-5 values
  __shared__ int   cj[4][4][B_N];     // persistent running top-4 indices
  __shared__ float cmn[4][B_N];       // persistent running min
  __shared__ float part[2][B_N];
  __shared__ float cst[2][B_N];
  __shared__ float bias[8];
  __shared__ float wt2[2];

  const int g = blockIdx.x;
  const int tid = threadIdx.x;
  const int b = tid & 63;
  const int kq = tid >> 6;

  unsigned int* flags = (unsigned int*)(ws + FLAG_F);
  unsigned int* epoch = (unsigned int*)(ws + EPOCH_F);

  // stage weights (resident all steps)
  for (int idx = tid; idx < 8 * I_N; idx += 256) {
    int rr = idx >> 8, k = idx & (I_N - 1);
    int grow = (rr >> 1) * H_N + 2 * g + (rr & 1);   // rr = gate*2 + jj
    Wx[k][rr] = W_ih[grow * I_N + k];
  }
  for (int idx = tid; idx < 8 * H_N; idx += 256) {
    int rr = idx >> 9, k = idx & (H_N - 1);
    int grow = (rr >> 1) * H_N + 2 * g + (rr & 1);
    Wh[k][rr] = W_hh[grow * H_N + k];
  }
  if (tid < 8) {
    int grow = (tid >> 1) * H_N + 2 * g + (tid & 1);
    bias[tid] = b_ih[grow] + b_hh[grow];
  }
  if (tid < 2) wt2[tid] = w_t[H_N + 2 * g + tid];
  if (tid < 128) cst[tid >> 6][tid & 63] = 0.0f;
  {  // init persistent running top-5 state: (q = tid>>6, b)
    cv[kq][0][b] = -3e38f; cv[kq][1][b] = -3e38f; cv[kq][2][b] = -3e38f;
    cv[kq][3][b] = -3e38f; cv[kq][4][b] = -3e38f;
    cj[kq][0][b] = 0; cj[kq][1][b] = 0; cj[kq][2][b] = 0; cj[kq][3][b] = 0;
    cmn[kq][b] = 3e38f;
  }
  __syncthreads();

  // prologue: x-part of step 0's matvec
  float xacc[8];
  #pragma unroll
  for (int r = 0; r < 8; ++r) xacc[r] = 0.0f;
  {
    const v4f* xp = (const v4f*)(ws + XT4_F) + b;
    v4f xv[16];
    #pragma unroll
    for (int j = 0; j < 16; ++j) xv[j] = xp[(kq * 16 + j) * 64];
    #pragma unroll
    for (int j = 0; j < 16; ++j) {
      #pragma unroll
      for (int u = 0; u < 4; ++u) {
        float v = xv[j][u];
        const float* wr = &Wx[4 * (kq * 16 + j) + u][0];
        #pragma unroll
        for (int r = 0; r < 8; ++r) xacc[r] += v * wr[r];
      }
    }
  }

  for (int i = 0; i < T_N; ++i) {
    // ---- S0: wait for step i-1 to be globally complete (no fences) ----
    if (i > 0) {
      if (g == 0) {
        while (ld_lic_u32(&flags[tid << 4]) < (unsigned)i)
          __builtin_amdgcn_s_sleep(1);
        __syncthreads();
        if (tid == 0) st_lic_u32(epoch, (unsigned)i);
      } else {
        if (tid == 0) {
          while (ld_lic_u32(epoch) < (unsigned)i)
            __builtin_amdgcn_s_sleep(1);
        }
      }
      __syncthreads();
    }

    // ---- Phase A: issue all loads (psum plane i, h slice i), then consume ----
    v4f pv[16];
    {
      const v4f* pp = (const v4f*)(ws + PSUM4_F) + (unsigned)i * 4096u + b;
      #pragma unroll
      for (int j = 0; j < 16; ++j) pv[j] = pp[(kq * 16 + j) * 64];
    }
    v4f hv[32];
    {
      const v4f* hp = (const v4f*)(ws + MEM4_F) + (unsigned)i * 8192u + b;  // mem[i] == h_out(i-1)
      #pragma unroll
      for (int j = 0; j < 32; ++j) hv[j] = hp[(kq * 32 + j) * 64];
    }
    float ps = 0.0f;
    #pragma unroll
    for (int j = 0; j < 16; ++j) ps += (pv[j][0] + pv[j][1]) + (pv[j][2] + pv[j][3]);
    psum[kq][b] = ps;

    float acc[8];
    #pragma unroll
    for (int r = 0; r < 8; ++r) acc[r] = xacc[r];
    #pragma unroll
    for (int j = 0; j < 32; ++j) {
      #pragma unroll
      for (int u = 0; u < 4; ++u) {
        float v = hv[j][u];
        const float* wr = &Wh[4 * (kq * 32 + j) + u][0];
        #pragma unroll
        for (int r = 0; r < 8; ++r) acc[r] += v * wr[r];
      }
    }
    #pragma unroll
    for (int r = 0; r < 8; ++r) red[kq][r][b] = acc[r];
    __syncthreads();  // S1

    // ---- Phase B: owner wave inserts t=i into its running top-5 ----
    if (kq == (i >> 6)) {
      float sc = psum[0][b] + psum[1][b] + psum[2][b] + psum[3][b];
      float v0 = cv[kq][0][b], v1 = cv[kq][1][b], v2 = cv[kq][2][b],
            v3 = cv[kq][3][b], v4 = cv[kq][4][b];
      int j0 = cj[kq][0][b], j1 = cj[kq][1][b], j2 = cj[kq][2][b], j3 = cj[kq][3][b];
      ins5(sc, i, v0, v1, v2, v3, v4, j0, j1, j2, j3);
      cv[kq][0][b] = v0; cv[kq][1][b] = v1; cv[kq][2][b] = v2;
      cv[kq][3][b] = v3; cv[kq][4][b] = v4;
      cj[kq][0][b] = j0; cj[kq][1][b] = j1; cj[kq][2][b] = j2; cj[kq][3][b] = j3;
      cmn[kq][b] = fminf(cmn[kq][b], sc);
    }
    __syncthreads();  // S2

    // ---- Phase C+D (tid<128): merge top-5, weights, LSTM cell, gather ----
    if (tid < 128) {
      float v0 = -3e38f, v1 = -3e38f, v2 = -3e38f, v3 = -3e38f, v4 = -3e38f;
      int j0 = 0, j1 = 0, j2 = 0, j3 = 0;
      float mn = 3e38f;
      #pragma unroll
      for (int q = 0; q < 4; ++q) {
        mn = fminf(mn, cmn[q][b]);
        ins5(cv[q][0][b], cj[q][0][b], v0, v1, v2, v3, v4, j0, j1, j2, j3);
        ins5(cv[q][1][b], cj[q][1][b], v0, v1, v2, v3, v4, j0, j1, j2, j3);
        ins5(cv[q][2][b], cj[q][2][b], v0, v1, v2, v3, v4, j0, j1, j2, j3);
        ins5(cv[q][3][b], cj[q][3][b], v0, v1, v2, v3, v4, j0, j1, j2, j3);
        ins5(cv[q][4][b], 0,           v0, v1, v2, v3, v4, j0, j1, j2, j3);  // rank>=5: value-only
      }
      float delta = ((i + 1) <= 5 ? mn : v4) + EPSF;
      float w0 = fmaxf(v0 - delta, 0.0f);
      float w1 = fmaxf(v1 - delta, 0.0f);
      float w2 = fmaxf(v2 - delta, 0.0f);
      float w3 = fmaxf(v3 - delta, 0.0f);
      float inv = 1.0f / (w0 + w1 + w2 + w3 + EPSF);
      w0 *= inv; w1 *= inv; w2 *= inv; w3 *= inv;

      const int jj = tid >> 6;
      float gi = red[0][  jj][b] + red[1][  jj][b] + red[2][  jj][b] + red[3][  jj][b] + bias[  jj];
      float gf = red[0][2+jj][b] + red[1][2+jj][b] + red[2][2+jj][b] + red[3][2+jj][b] + bias[2+jj];
      float gg = red[0][4+jj][b] + red[1][4+jj][b] + red[2][4+jj][b] + red[3][4+jj][b] + bias[4+jj];
      float go = red[0][6+jj][b] + red[1][6+jj][b] + red[2][6+jj][b] + red[3][6+jj][b] + bias[6+jj];
      float cn = sigf(gf) * cst[jj][b] + sigf(gi) * tanhf(gg);
      float hn = sigf(go) * tanhf(cn);
      cst[jj][b] = cn;

      const int hd = 2 * g + jj;
      const unsigned hoff = (unsigned)(hd >> 2) * 256u + (unsigned)b * 4u + (unsigned)(hd & 3);
      const float* mb = ws + MEM4_F + hoff;
      float m = w0 * mb[(unsigned)j0 * 32768u] + w1 * mb[(unsigned)j1 * 32768u]
              + w2 * mb[(unsigned)j2 * 32768u] + w3 * mb[(unsigned)j3 * 32768u];
      float ho = hn + m;
      st_lic_f32(ws + MEM4_F + (unsigned)(i + 1) * 32768u + hoff, ho);  // cross-WG: to LIC
      ws[MSEQ4_F + (unsigned)i * 32768u + hoff] = m;                    // read by out_gemm only
      part[jj][b] = tanhf(ho) * wt2[jj];
    }
    __syncthreads();  // S3 — drains vmcnt(0) per wave: all mem stores at LIC

    // ---- Phase E: publish score partial (write-once plane i+1); arrive ----
    if (tid < 64) {
      st_lic_f32(ws + PSUM4_F + (unsigned)(i + 1) * 16384u + (unsigned)(g >> 2) * 256u
                 + (unsigned)tid * 4u + (unsigned)(g & 3),
                 part[0][tid] + part[1][tid]);
    }
    if (tid == 0) {
      asm volatile("s_waitcnt vmcnt(0)" ::: "memory");  // psum stores at LIC
      st_lic_u32(&flags[g << 4], (unsigned)(i + 1));
    }

    // ---- overlap: x-part of NEXT step's matvec (static xT4, no dependency) ----
    if (i + 1 < T_N) {
      const v4f* xp = (const v4f*)(ws + XT4_F) + (unsigned)(i + 1) * 4096u + b;
      v4f xv[16];
      #pragma unroll
      for (int j = 0; j < 16; ++j) xv[j] = xp[(kq * 16 + j) * 64];
      #pragma unroll
      for (int r = 0; r < 8; ++r) xacc[r] = 0.0f;
      #pragma unroll
      for (int j = 0; j < 16; ++j) {
        #pragma unroll
        for (int u = 0; u < 4; ++u) {
          float v = xv[j][u];
          const float* wr = &Wx[4 * (kq * 16 + j) + u][0];
          #pragma unroll
          for (int r = 0; r < 8; ++r) xacc[r] += v * wr[r];
        }
      }
    }
  }
}

// out[t,b,c] = sum_d feats[t,d,b]*fcwT[d,c] + fc_b[c];
// feats h-half == mem4[t+1], m-half == mseq4[t] (packed [k4][b][4]).
__launch_bounds__(256, 4)
__global__ void out_gemm(const float* __restrict__ ws, const float* __restrict__ fc_b,
                         float* __restrict__ out) {
  __shared__ float fw[64][16];
  const int t = blockIdx.x >> 2, cg = blockIdx.x & 3;
  const int tid = threadIdx.x, b = tid & 63, cs = (tid >> 6) * 4;
  float acc[4] = {0.0f, 0.0f, 0.0f, 0.0f};
  const v4f* hsrc = (const v4f*)(ws + MEM4_F) + (unsigned)(t + 1) * 8192u + b;
  const v4f* msrc = (const v4f*)(ws + MSEQ4_F) + (unsigned)t * 8192u + b;
  for (int half = 0; half < 2; ++half) {
    const v4f* src = half ? msrc : hsrc;
    for (int dt = 0; dt < 512; dt += 64) {
      __syncthreads();
      for (int u = tid; u < 1024; u += 256) {
        int dd = u >> 4, cc = u & 15;
        fw[dd][cc] = ws[FCWT_F + (unsigned)(half * 512 + dt + dd) * 64u + cg * 16 + cc];
      }
      __syncthreads();
      #pragma unroll 4
      for (int j = 0; j < 16; ++j) {
        v4f f4 = src[(unsigned)(dt / 4 + j) * 64u];
        #pragma unroll
        for (int u = 0; u < 4; ++u) {
          float f = f4[u];
          const float* wr = &fw[4 * j + u][cs];
          #pragma unroll
          for (int c4 = 0; c4 < 4; ++c4) acc[c4] += f * wr[c4];
        }
      }
    }
  }
  float* op = out + ((unsigned)t * 64u + b) * 64u + cg * 16 + cs;
  #pragma unroll
  for (int c4 = 0; c4 < 4; ++c4) op[c4] = acc[c4] + fc_b[cg * 16 + cs + c4];
}

extern "C" void kernel_launch(void* const* d_in, const int* in_sizes, int n_in,
                              void* d_out, int out_size, void* d_ws, size_t ws_size,
                              hipStream_t stream) {
  const float* x    = (const float*)d_in[0];
  const float* W_ih = (const float*)d_in[1];
  const float* W_hh = (const float*)d_in[2];
  const float* b_ih = (const float*)d_in[3];
  const float* b_hh = (const float*)d_in[4];
  const float* w_t  = (const float*)d_in[5];
  const float* fc_w = (const float*)d_in[6];
  const float* fc_b = (const float*)d_in[7];
  float* out = (float*)d_out;
  float* ws  = (float*)d_ws;

  if (ws_size < (size_t)TOT_F * 4u) {
    poison_k<<<(out_size + 255) / 256, 256, 0, stream>>>(out, out_size);
    return;
  }

  hipMemsetAsync(ws + MEM4_F, 0, (size_t)32768u * 4u, stream);     // mem[0] = 0
  hipMemsetAsync(ws + PSUM4_F, 0, (size_t)16384u * 4u, stream);    // psum plane 0
  hipMemsetAsync(ws + FLAG_F, 0, (size_t)(TOT_F - FLAG_F) * 4u, stream);  // flags+epoch

  init_k<<<1040, 256, 0, stream>>>(x, fc_w, ws);
  lstm_main<<<256, 256, 0, stream>>>(W_ih, W_hh, b_ih, b_hh, w_t, ws);
  out_gemm<<<1024, 256, 0, stream>>>(ws, fc_b, out);
}

// Round 6
// 2363.817 us; speedup vs baseline: 7.4012x; 1.2872x over previous
//
#include <hip/hip_runtime.h>

// ---------------------------------------------------------------------------
// self_LSTM_sparse_attn — MI355X persistent-kernel, round 6.
//
// R5 post-mortem: 11.9us/step; VALU 3.1us; rest = barrier choreography
// (2 serial LIC hops + collector) and Phase-B/C LDS round-trips. This round:
//   (1) per-wave producer wait: wave kq's Phase-A inputs (psum quarter +
//       mem quarter) are written exactly by WGs [64kq,64kq+64). Flags are
//       packed u32[256]; lane b of wave kq polls flag[64kq+b] directly.
//       WG0-collector + epoch hop deleted; waves start loads as soon as
//       THEIR producers arrived (straggler overlap).
//   (2) registerized replicated top-5: every thread keeps the full running
//       top-5 (v0..v4,j0..j3,mn) for its batch lane in registers; one ins5
//       per step. Phase B, barrier S2, the 25-ins5 merge and 10KB LDS gone.
//       Insertion order (t ascending) identical => bit-identical results.
//
// Carried invariants (R5-verified): all cross-WG data write-once per step,
// stores go direct to LIC via sc0 sc1 (no fences anywhere); flag[g]=i+1 is
// stored only after vmcnt(0) drain of g's plane-(i+1) stores; readers' L2
// can only acquire a shared line after its unique LIC write.
// Algorithm (R2-R5-verified): s_h cancels in attention weights; w <=4-sparse;
// WG g owns h dims {2g,2g+1}; weights LDS-resident; mem[i] == h_out(i-1).
// ---------------------------------------------------------------------------

#define T_N 256
#define B_N 64
#define I_N 256
#define H_N 512
#define C_N 64
#define EPSF 1e-7f

typedef float v4f __attribute__((ext_vector_type(4)));

// ws layout (float offsets). Packed layouts: [..][k4][b][u] u=k&3.
#define XT4_F   0u          // [T][64][64][4]    x packed          (4,194,304)
#define MEM4_F  4194304u    // [T+1][128][64][4] h_out history     (8,421,376)
#define MSEQ4_F 12615680u   // [T][128][64][4]   m_seq             (8,388,608)
#define PSUM4_F 21004288u   // [T+1][64][64][4]  score partials, write-once (4,210,688)
#define FCWT_F  25214976u   // [2H][C] fc_w transposed             (65,536)
#define FLAG_F  25280512u   // [256] arrival flags, packed u32     (256)
#define TOT_F   25280768u

__device__ __forceinline__ float sigf(float x) { return 1.0f / (1.0f + expf(-x)); }

// direct-to-LIC (coherence point) ops — no fences needed anywhere.
__device__ __forceinline__ void st_lic_f32(float* p, float v) {
  asm volatile("global_store_dword %0, %1, off sc0 sc1" :: "v"(p), "v"(v) : "memory");
}
__device__ __forceinline__ void st_lic_u32(unsigned* p, unsigned v) {
  asm volatile("global_store_dword %0, %1, off sc0 sc1" :: "v"(p), "v"(v) : "memory");
}
__device__ __forceinline__ unsigned ld_lic_u32(const unsigned* p) {
  unsigned r;
  asm volatile("global_load_dword %0, %1, off sc0 sc1\n\ts_waitcnt vmcnt(0)"
               : "=v"(r) : "v"(p) : "memory");
  return r;
}

__device__ __forceinline__ void ins5(float s, int t,
                                     float& v0, float& v1, float& v2, float& v3, float& v4,
                                     int& j0, int& j1, int& j2, int& j3) {
  if (s > v4) {
    if (s > v0)      { v4=v3; v3=v2; j3=j2; v2=v1; j2=j1; v1=v0; j1=j0; v0=s; j0=t; }
    else if (s > v1) { v4=v3; v3=v2; j3=j2; v2=v1; j2=j1; v1=s; j1=t; }
    else if (s > v2) { v4=v3; v3=v2; j3=j2; v2=s; j2=t; }
    else if (s > v3) { v4=v3; v3=s; j3=t; }
    else             { v4=s; }
  }
}

__global__ void poison_k(float* out, int n) {
  int i = blockIdx.x * 256 + threadIdx.x;
  if (i < n) out[i] = __int_as_float(0x7fc00000);
}

// blocks 0..1023: x -> xT4 packed; blocks 1024..1039: fc_w -> fcwT[d][c]
__global__ void init_k(const float* __restrict__ x, const float* __restrict__ fc_w,
                       float* __restrict__ ws) {
  __shared__ float tile[64][65];
  const int blk = blockIdx.x, tid = threadIdx.x;
  if (blk < 1024) {
    const int t = blk >> 2, k0 = (blk & 3) * 64;
    for (int u = tid; u < 4096; u += 256) {
      int bb = u >> 6, kk = u & 63;
      tile[kk][bb] = x[((unsigned)t * 64u + bb) * 256u + k0 + kk];
    }
    __syncthreads();
    for (int u = tid; u < 4096; u += 256) {
      int kk = u >> 6, bb = u & 63;
      int k = k0 + kk;
      ws[XT4_F + (unsigned)t * 16384u + (unsigned)(k >> 2) * 256u
         + (unsigned)bb * 4u + (unsigned)(k & 3)] = tile[kk][bb];
    }
  } else {
    const int d0 = (blk - 1024) * 64;
    for (int u = tid; u < 4096; u += 256) {
      int cc = u >> 6, dd = u & 63;
      tile[dd][cc] = fc_w[(unsigned)cc * 1024u + d0 + dd];
    }
    __syncthreads();
    for (int u = tid; u < 4096; u += 256) {
      int dd = u >> 6, cc = u & 63;
      ws[FCWT_F + (unsigned)(d0 + dd) * 64u + cc] = tile[dd][cc];
    }
  }
}

__launch_bounds__(256, 1)
__global__ void lstm_main(const float* __restrict__ W_ih, const float* __restrict__ W_hh,
                          const float* __restrict__ b_ih, const float* __restrict__ b_hh,
                          const float* __restrict__ w_t, float* __restrict__ ws) {
  __shared__ float Wx[I_N][8];        // 8 KB
  __shared__ float Wh[H_N][8];        // 16 KB
  __shared__ float red[4][8][B_N];    // 8 KB gate partials per k-quarter
  __shared__ float psum[4][B_N];      // 1 KB
  __shared__ float part[2][B_N];
  __shared__ float cst[2][B_N];
  __shared__ float bias[8];
  __shared__ float wt2[2];

  const int g = blockIdx.x;
  const int tid = threadIdx.x;
  const int b = tid & 63;
  const int kq = tid >> 6;

  unsigned int* flags = (unsigned int*)(ws + FLAG_F);

  // stage weights (resident all steps)
  for (int idx = tid; idx < 8 * I_N; idx += 256) {
    int rr = idx >> 8, k = idx & (I_N - 1);
    int grow = (rr >> 1) * H_N + 2 * g + (rr & 1);   // rr = gate*2 + jj
    Wx[k][rr] = W_ih[grow * I_N + k];
  }
  for (int idx = tid; idx < 8 * H_N; idx += 256) {
    int rr = idx >> 9, k = idx & (H_N - 1);
    int grow = (rr >> 1) * H_N + 2 * g + (rr & 1);
    Wh[k][rr] = W_hh[grow * H_N + k];
  }
  if (tid < 8) {
    int grow = (tid >> 1) * H_N + 2 * g + (tid & 1);
    bias[tid] = b_ih[grow] + b_hh[grow];
  }
  if (tid < 2) wt2[tid] = w_t[H_N + 2 * g + tid];
  if (tid < 128) cst[tid >> 6][tid & 63] = 0.0f;
  __syncthreads();

  // per-thread replicated running top-5 state (batch lane b)
  float v0 = -3e38f, v1 = -3e38f, v2 = -3e38f, v3 = -3e38f, v4 = -3e38f;
  int j0 = 0, j1 = 0, j2 = 0, j3 = 0;
  float mn = 3e38f;

  // prologue: x-part of step 0's matvec
  float xacc[8];
  #pragma unroll
  for (int r = 0; r < 8; ++r) xacc[r] = 0.0f;
  {
    const v4f* xp = (const v4f*)(ws + XT4_F) + b;
    v4f xv[16];
    #pragma unroll
    for (int j = 0; j < 16; ++j) xv[j] = xp[(kq * 16 + j) * 64];
    #pragma unroll
    for (int j = 0; j < 16; ++j) {
      #pragma unroll
      for (int u = 0; u < 4; ++u) {
        float v = xv[j][u];
        const float* wr = &Wx[4 * (kq * 16 + j) + u][0];
        #pragma unroll
        for (int r = 0; r < 8; ++r) xacc[r] += v * wr[r];
      }
    }
  }

  for (int i = 0; i < T_N; ++i) {
    // ---- S0: per-wave producer wait. Wave kq's Phase-A inputs are written
    // exactly by WGs [64kq, 64kq+64): lane b polls flag[64kq+b]. ----
    if (i > 0) {
      const unsigned* fp = flags + ((kq << 6) | b);
      while (ld_lic_u32(fp) < (unsigned)i) __builtin_amdgcn_s_sleep(1);
    }

    // ---- Phase A: issue all loads (psum quarter, mem quarter), consume ----
    v4f pv[16];
    {
      const v4f* pp = (const v4f*)(ws + PSUM4_F) + (unsigned)i * 4096u + b;
      #pragma unroll
      for (int j = 0; j < 16; ++j) pv[j] = pp[(kq * 16 + j) * 64];
    }
    v4f hv[32];
    {
      const v4f* hp = (const v4f*)(ws + MEM4_F) + (unsigned)i * 8192u + b;  // mem[i] == h_out(i-1)
      #pragma unroll
      for (int j = 0; j < 32; ++j) hv[j] = hp[(kq * 32 + j) * 64];
    }
    float ps = 0.0f;
    #pragma unroll
    for (int j = 0; j < 16; ++j) ps += (pv[j][0] + pv[j][1]) + (pv[j][2] + pv[j][3]);
    psum[kq][b] = ps;

    float acc[8];
    #pragma unroll
    for (int r = 0; r < 8; ++r) acc[r] = xacc[r];
    #pragma unroll
    for (int j = 0; j < 32; ++j) {
      #pragma unroll
      for (int u = 0; u < 4; ++u) {
        float v = hv[j][u];
        const float* wr = &Wh[4 * (kq * 32 + j) + u][0];
        #pragma unroll
        for (int r = 0; r < 8; ++r) acc[r] += v * wr[r];
      }
    }
    #pragma unroll
    for (int r = 0; r < 8; ++r) red[kq][r][b] = acc[r];
    __syncthreads();  // S1

    // ---- Phase B (all threads, registers): insert score(i) into top-5 ----
    float sc = psum[0][b] + psum[1][b] + psum[2][b] + psum[3][b];
    ins5(sc, i, v0, v1, v2, v3, v4, j0, j1, j2, j3);
    mn = fminf(mn, sc);

    // ---- Phase C+D (tid<128): weights, LSTM cell, sparse gather, writes ----
    if (tid < 128) {
      float delta = ((i + 1) <= 5 ? mn : v4) + EPSF;
      float w0 = fmaxf(v0 - delta, 0.0f);
      float w1 = fmaxf(v1 - delta, 0.0f);
      float w2 = fmaxf(v2 - delta, 0.0f);
      float w3 = fmaxf(v3 - delta, 0.0f);
      float inv = 1.0f / (w0 + w1 + w2 + w3 + EPSF);
      w0 *= inv; w1 *= inv; w2 *= inv; w3 *= inv;

      const int jj = tid >> 6;
      float gi = red[0][  jj][b] + red[1][  jj][b] + red[2][  jj][b] + red[3][  jj][b] + bias[  jj];
      float gf = red[0][2+jj][b] + red[1][2+jj][b] + red[2][2+jj][b] + red[3][2+jj][b] + bias[2+jj];
      float gg = red[0][4+jj][b] + red[1][4+jj][b] + red[2][4+jj][b] + red[3][4+jj][b] + bias[4+jj];
      float go = red[0][6+jj][b] + red[1][6+jj][b] + red[2][6+jj][b] + red[3][6+jj][b] + bias[6+jj];
      float cn = sigf(gf) * cst[jj][b] + sigf(gi) * tanhf(gg);
      float hn = sigf(go) * tanhf(cn);
      cst[jj][b] = cn;

      const int hd = 2 * g + jj;
      const unsigned hoff = (unsigned)(hd >> 2) * 256u + (unsigned)b * 4u + (unsigned)(hd & 3);
      const float* mb = ws + MEM4_F + hoff;
      float m = w0 * mb[(unsigned)j0 * 32768u] + w1 * mb[(unsigned)j1 * 32768u]
              + w2 * mb[(unsigned)j2 * 32768u] + w3 * mb[(unsigned)j3 * 32768u];
      float ho = hn + m;
      st_lic_f32(ws + MEM4_F + (unsigned)(i + 1) * 32768u + hoff, ho);  // cross-WG: to LIC
      ws[MSEQ4_F + (unsigned)i * 32768u + hoff] = m;                    // read by out_gemm only
      part[jj][b] = tanhf(ho) * wt2[jj];
    }
    __syncthreads();  // S3 — per-wave vmcnt(0) drain: waves 0/1's stores at LIC

    // ---- Phase E: publish score partial (write-once plane i+1); arrive ----
    if (tid < 64) {
      st_lic_f32(ws + PSUM4_F + (unsigned)(i + 1) * 16384u + (unsigned)(g >> 2) * 256u
                 + (unsigned)tid * 4u + (unsigned)(g & 3),
                 part[0][tid] + part[1][tid]);
    }
    if (tid == 0) {
      asm volatile("s_waitcnt vmcnt(0)" ::: "memory");  // psum stores at LIC
      st_lic_u32(&flags[g], (unsigned)(i + 1));
    }

    // ---- overlap: x-part of NEXT step's matvec (static xT4, no dependency) ----
    if (i + 1 < T_N) {
      const v4f* xp = (const v4f*)(ws + XT4_F) + (unsigned)(i + 1) * 4096u + b;
      v4f xv[16];
      #pragma unroll
      for (int j = 0; j < 16; ++j) xv[j] = xp[(kq * 16 + j) * 64];
      #pragma unroll
      for (int r = 0; r < 8; ++r) xacc[r] = 0.0f;
      #pragma unroll
      for (int j = 0; j < 16; ++j) {
        #pragma unroll
        for (int u = 0; u < 4; ++u) {
          float v = xv[j][u];
          const float* wr = &Wx[4 * (kq * 16 + j) + u][0];
          #pragma unroll
          for (int r = 0; r < 8; ++r) xacc[r] += v * wr[r];
        }
      }
    }
  }
}

// out[t,b,c] = sum_d feats[t,d,b]*fcwT[d,c] + fc_b[c];
// feats h-half == mem4[t+1], m-half == mseq4[t] (packed [k4][b][4]).
__launch_bounds__(256, 4)
__global__ void out_gemm(const float* __restrict__ ws, const float* __restrict__ fc_b,
                         float* __restrict__ out) {
  __shared__ float fw[64][16];
  const int t = blockIdx.x >> 2, cg = blockIdx.x & 3;
  const int tid = threadIdx.x, b = tid & 63, cs = (tid >> 6) * 4;
  float acc[4] = {0.0f, 0.0f, 0.0f, 0.0f};
  const v4f* hsrc = (const v4f*)(ws + MEM4_F) + (unsigned)(t + 1) * 8192u + b;
  const v4f* msrc = (const v4f*)(ws + MSEQ4_F) + (unsigned)t * 8192u + b;
  for (int half = 0; half < 2; ++half) {
    const v4f* src = half ? msrc : hsrc;
    for (int dt = 0; dt < 512; dt += 64) {
      __syncthreads();
      for (int u = tid; u < 1024; u += 256) {
        int dd = u >> 4, cc = u & 15;
        fw[dd][cc] = ws[FCWT_F + (unsigned)(half * 512 + dt + dd) * 64u + cg * 16 + cc];
      }
      __syncthreads();
      #pragma unroll 4
      for (int j = 0; j < 16; ++j) {
        v4f f4 = src[(unsigned)(dt / 4 + j) * 64u];
        #pragma unroll
        for (int u = 0; u < 4; ++u) {
          float f = f4[u];
          const float* wr = &fw[4 * j + u][cs];
          #pragma unroll
          for (int c4 = 0; c4 < 4; ++c4) acc[c4] += f * wr[c4];
        }
      }
    }
  }
  float* op = out + ((unsigned)t * 64u + b) * 64u + cg * 16 + cs;
  #pragma unroll
  for (int c4 = 0; c4 < 4; ++c4) op[c4] = acc[c4] + fc_b[cg * 16 + cs + c4];
}

extern "C" void kernel_launch(void* const* d_in, const int* in_sizes, int n_in,
                              void* d_out, int out_size, void* d_ws, size_t ws_size,
                              hipStream_t stream) {
  const float* x    = (const float*)d_in[0];
  const float* W_ih = (const float*)d_in[1];
  const float* W_hh = (const float*)d_in[2];
  const float* b_ih = (const float*)d_in[3];
  const float* b_hh = (const float*)d_in[4];
  const float* w_t  = (const float*)d_in[5];
  const float* fc_w = (const float*)d_in[6];
  const float* fc_b = (const float*)d_in[7];
  float* out = (float*)d_out;
  float* ws  = (float*)d_ws;

  if (ws_size < (size_t)TOT_F * 4u) {
    poison_k<<<(out_size + 255) / 256, 256, 0, stream>>>(out, out_size);
    return;
  }

  hipMemsetAsync(ws + MEM4_F, 0, (size_t)32768u * 4u, stream);     // mem[0] = 0
  hipMemsetAsync(ws + PSUM4_F, 0, (size_t)16384u * 4u, stream);    // psum plane 0
  hipMemsetAsync(ws + FLAG_F, 0, 256u * 4u, stream);               // flags

  init_k<<<1040, 256, 0, stream>>>(x, fc_w, ws);
  lstm_main<<<256, 256, 0, stream>>>(W_ih, W_hh, b_ih, b_hh, w_t, ws);
  out_gemm<<<1024, 256, 0, stream>>>(ws, fc_b, out);
}